// Round 11
// baseline (4184.827 us; speedup 1.0000x reference)
//
#include <hip/hip_runtime.h>

#define B_ 64
#define T_ 512
#define D_ 512
#define N_ 1024
#define G_ 4096   // 4*N

typedef _Float16 f16;
typedef __attribute__((ext_vector_type(8))) _Float16 f16x8;
typedef __attribute__((ext_vector_type(4))) _Float16 f16x4;
typedef __attribute__((ext_vector_type(4))) float f32x4_t;
typedef unsigned long long u64;
typedef __attribute__((ext_vector_type(4))) unsigned int u32x4;

static __device__ __forceinline__ f32x4_t mfma16(f16x8 a, f16x8 b, f32x4_t c) {
    return __builtin_amdgcn_mfma_f32_16x16x32_f16(a, b, c, 0, 0, 0);
}

static __device__ __forceinline__ float fsig(float x) {
    return 1.f / (1.f + __expf(-x));
}
static __device__ __forceinline__ float ftanh(float x) {
    return 1.f - 2.f / (__expf(2.f * x) + 1.f);
}

// workspace map (inside first 4MB, overlapping dead WxT)
#define PAYB   131072        // one payload copy: [bg4][32KB]
#define OFF_TAG 0x60000      // 3*PAYB; tags: 4*256 u32 = 4KB

// ---------------------------------------------------------------------------
// Phase 0: WxT[g][d] = (f16) W[d][g]   (validated R1)
// ---------------------------------------------------------------------------
__global__ __launch_bounds__(256) void k_transpose_wx(const float* __restrict__ W,
                                                      f16* __restrict__ WxT) {
    __shared__ float tile[64][65];
    int bx = blockIdx.x;
    int dt = bx >> 6, gt = bx & 63;
    int d0 = dt * 64, g0 = gt * 64;
    int tid = threadIdx.x;
    for (int e = tid; e < 4096; e += 256) {
        int r = e >> 6, c = e & 63;
        tile[r][c] = W[(size_t)(d0 + r) * G_ + (g0 + c)];
    }
    __syncthreads();
    for (int e = tid; e < 4096; e += 256) {
        int r = e >> 6, c = e & 63;
        WxT[(size_t)(g0 + r) * D_ + (d0 + c)] = (f16)tile[c][r];
    }
}

// ---------------------------------------------------------------------------
// Phase 1: xp[t][g][b] = (f16)( x@Wx + bias )   (validated R1)
// ---------------------------------------------------------------------------
__global__ __launch_bounds__(256, 2) void k_xproj(const float* __restrict__ x,
                                                  const f16* __restrict__ WxT,
                                                  const float* __restrict__ bias,
                                                  f16* __restrict__ xp) {
    __shared__ __align__(16) f16 alds[64 * 512];   // 64 KB
    int t = blockIdx.x;
    int tid = threadIdx.x;
    int w = tid >> 6, l = tid & 63;

    for (int ch = tid; ch < 4096; ch += 256) {
        int b  = ch >> 6;
        int d0 = (ch & 63) << 3;
        const float* px = x + ((size_t)b * T_ + t) * D_ + d0;
        float4 v0 = *(const float4*)px;
        float4 v1 = *(const float4*)(px + 4);
        f16x8 s;
        s[0] = (f16)v0.x; s[1] = (f16)v0.y; s[2] = (f16)v0.z; s[3] = (f16)v0.w;
        s[4] = (f16)v1.x; s[5] = (f16)v1.y; s[6] = (f16)v1.z; s[7] = (f16)v1.w;
        unsigned byteoff = ((unsigned)(b * 512 + d0) * 2u) ^ ((unsigned)(b & 7) << 4);
        *(f16x8*)((char*)alds + byteoff) = s;
    }
    __syncthreads();

    const int gw = w * 1024;
    const int qk = (l >> 4) << 3;
    const int cc = l & 15;

    for (int gtb = 0; gtb < 16; ++gtb) {
        f32x4_t acc[4][4];
        #pragma unroll
        for (int a = 0; a < 4; ++a)
            #pragma unroll
            for (int m = 0; m < 4; ++m) acc[a][m] = f32x4_t{0.f, 0.f, 0.f, 0.f};

        for (int ks = 0; ks < 16; ++ks) {
            f16x8 afr[4];
            #pragma unroll
            for (int mb = 0; mb < 4; ++mb) {
                int b = mb * 16 + cc;
                int d = ks * 32 + qk;
                unsigned byteoff = ((unsigned)(b * 512 + d) * 2u) ^ ((unsigned)(b & 7) << 4);
                afr[mb] = *(const f16x8*)((const char*)alds + byteoff);
            }
            #pragma unroll
            for (int gl = 0; gl < 4; ++gl) {
                int g = gw + (gtb * 4 + gl) * 16 + cc;
                f16x8 bfr = *(const f16x8*)(WxT + (size_t)g * D_ + ks * 32 + qk);
                #pragma unroll
                for (int mb = 0; mb < 4; ++mb)
                    acc[gl][mb] = mfma16(afr[mb], bfr, acc[gl][mb]);
            }
        }
        #pragma unroll
        for (int gl = 0; gl < 4; ++gl) {
            int g = gw + (gtb * 4 + gl) * 16 + cc;
            float bg = bias[g];
            #pragma unroll
            for (int mb = 0; mb < 4; ++mb) {
                int b0 = mb * 16 + ((l >> 4) << 2);
                f16x4 sv;
                sv[0] = (f16)(acc[gl][mb][0] + bg);
                sv[1] = (f16)(acc[gl][mb][1] + bg);
                sv[2] = (f16)(acc[gl][mb][2] + bg);
                sv[3] = (f16)(acc[gl][mb][3] + bg);
                *(f16x4*)(xp + ((size_t)t * G_ + g) * B_ + b0) = sv;
            }
        }
    }
}

// ---------------------------------------------------------------------------
// Phase 2: WAVE-AUTONOMOUS recurrence. R11 delta vs R10 (validated 1.61ms):
// wave w owns FULL K x n-tile nt=w (32 MFMAs, same count) -> output tile is
// complete in-wave -> NO cross-wave LDS reduce, NO __syncthreads anywhere in
// the loop. Gate regroup = tiny wave-private LDS exchange (write b128,
// lgkmcnt(0), 4 scalar reads - lockstep wave, in-order LDS, no barrier).
// Producer/publish/ack/tag protocol BIT-IDENTICAL to R10.
// Consumer waits on all 256 quad-tags of its bg (4 tags/lane, one dwordx4) -
// same dependency as before, previously enforced via the barrier.
// ---------------------------------------------------------------------------
__global__ __launch_bounds__(256, 1) void k_recur11(const float* __restrict__ W,
                                                    const f16* __restrict__ xp,
                                                    char* __restrict__ wsb,
                                                    float* __restrict__ out) {
    __shared__ __align__(16) float pexch[4][64][4];   // per-wave exchange, 4KB

    const int wg  = blockIdx.x;
    const int tid = threadIdx.x;
    const int w   = tid >> 6;
    const int l   = tid & 63;
    const int bg  = wg >> 6;
    const int ci  = wg & 63;

    const int lb    = l & 15;       // elementwise: batch
    const int dh    = l >> 4;       // elementwise: h-col offset within quad
    const int nh    = ci * 16 + w * 4 + dh;
    const int bglob = bg * 16 + lb;

    char*     const pay  = wsb;                      // 3 x 128 KB
    unsigned* const tags = (unsigned*)(wsb + OFF_TAG);

    // ---- Wh B-fragments for tile nt=w, FULL K: bf[32] (128 VGPR) ----
    f16x8 bf[32];
    {
        const int kq = l >> 4, ty = (l >> 2) & 3, dcl = l & 3;
        const int gc = ty * 1024 + ci * 16 + w * 4 + dcl;
        #pragma unroll
        for (int kk = 0; kk < 32; ++kk) {
            #pragma unroll
            for (int i = 0; i < 8; ++i) {
                int k = kk * 32 + kq * 8 + i;
                bf[kk][i] = (f16)W[(size_t)(D_ + k) * G_ + gc];
            }
        }
    }

    // ---- producer addressing (R8/R10-validated pure-h slot layout) ----
    const int nq  = ci * 16 + w * 4;
    const int ksq = nq >> 5;
    const int q8  = (nq & 31) >> 3;
    const size_t st_off = (size_t)bg * 32768
                        + ((size_t)(ksq * 64 + q8 * 16 + lb) << 4)
                        + (size_t)(w & 1) * 8;
    const bool do_st = (dh == 0);

    // ---- consumer addressing: full K -> lane l reads slot (ks*64 + l) ----
    const size_t ld_off = (size_t)bg * 32768 + ((size_t)l << 4);

    // tags: producer quad (ci,w) publishes one; consumer polls all 256 of bg
    unsigned* const tag_st = tags + (bg * 256 + ci * 4 + w);
    const char*     tag_ld = (const char*)(tags + bg * 256) + ((size_t)l << 4);

    // ---- init: zero payload buf0 (h_0 = 0), ack, tag = 1 ----
    if (do_st)
        __hip_atomic_store((u64*)(pay + st_off), 0ull,
                           __ATOMIC_RELAXED, __HIP_MEMORY_SCOPE_AGENT);
    asm volatile("s_waitcnt vmcnt(0)" ::: "memory");
    if (l == 0)
        __hip_atomic_store(tag_st, 1u, __ATOMIC_RELAXED, __HIP_MEMORY_SCOPE_AGENT);

    float cst = 0.f;
    int cur = 0, nxt = 1;

    for (int t = 0; t < T_; ++t) {
        // xp loads: non-temporal, issued early (HBM latency hides under poll)
        const unsigned short* xpp = (const unsigned short*)xp
                                  + (size_t)t * G_ * B_ + bglob;
        f16 xg0 = __builtin_bit_cast(f16, __builtin_nontemporal_load(xpp + (size_t)(0 * 1024 + nh) * B_));
        f16 xg1 = __builtin_bit_cast(f16, __builtin_nontemporal_load(xpp + (size_t)(1 * 1024 + nh) * B_));
        f16 xg2 = __builtin_bit_cast(f16, __builtin_nontemporal_load(xpp + (size_t)(2 * 1024 + nh) * B_));
        f16 xg3 = __builtin_bit_cast(f16, __builtin_nontemporal_load(xpp + (size_t)(3 * 1024 + nh) * B_));

        // ---- poll all 256 producer-quad tags (4/lane via one dwordx4) ----
        {
            const unsigned tgt = (unsigned)(t + 1);
            while (true) {
                u32x4 tv;
                asm volatile("global_load_dwordx4 %0, %1, off sc0 sc1\n\t"
                             "s_waitcnt vmcnt(0)"
                             : "=&v"(tv) : "v"(tag_ld) : "memory");
                bool ok = (tv[0] >= tgt) && (tv[1] >= tgt)
                       && (tv[2] >= tgt) && (tv[3] >= tgt);
                if (__all(ok)) break;
                __builtin_amdgcn_s_sleep(1);
            }
        }

        // ---- payload: 32 x 16B coherent loads (full K), once ----
        f16x8 af[32];
        {
            const char* pl = pay + (size_t)cur * PAYB + ld_off;
            #pragma unroll
            for (int kk = 0; kk < 32; ++kk)
                asm volatile("global_load_dwordx4 %0, %1, off sc0 sc1"
                             : "=&v"(af[kk]) : "v"(pl + kk * 1024) : "memory");
        }
        asm volatile("s_waitcnt vmcnt(0)" ::: "memory");
        __builtin_amdgcn_sched_barrier(0);   // rule 18: keep MFMA after the wait

        // ---- 32 MFMAs, 4 interleaved accumulator chains (ILP=4) ----
        f32x4_t acc[4];
        #pragma unroll
        for (int c = 0; c < 4; ++c) acc[c] = f32x4_t{0.f, 0.f, 0.f, 0.f};
        #pragma unroll
        for (int kk = 0; kk < 32; ++kk)
            acc[kk & 3] = mfma16(af[kk], bf[kk], acc[kk & 3]);
        f32x4_t fa = (acc[0] + acc[1]) + (acc[2] + acc[3]);

        // ---- wave-private gate exchange (no barrier) ----
        // C layout: this lane holds rows (l>>4)*4+j, col l&15 of the 16x16
        // (batch x gatecol) tile. Elementwise lane (lb, dh) needs
        // (row=lb, col=ty*4+dh) for ty=0..3 -> lane ((lb>>2)<<4)|(ty*4+dh),
        // reg lb&3.
        *(f32x4_t*)(&pexch[w][l][0]) = fa;
        asm volatile("s_waitcnt lgkmcnt(0)" ::: "memory");
        __builtin_amdgcn_sched_barrier(0);

        const int rg = lb & 3, lhi = (lb >> 2) << 4;
        float g0 = pexch[w][lhi | (0 * 4 + dh)][rg] + (float)xg0;
        float g1 = pexch[w][lhi | (1 * 4 + dh)][rg] + (float)xg1;
        float g2 = pexch[w][lhi | (2 * 4 + dh)][rg] + (float)xg2;
        float g3 = pexch[w][lhi | (3 * 4 + dh)][rg] + (float)xg3;

        float si = fsig(g0);
        float tj = ftanh(g1);
        float sf = fsig(g2 + 1.f);
        float so = fsig(g3);
        cst = cst * sf + si * tj;
        float h = ftanh(cst) * so;

        // ---- publish: payload stores -> wave ack -> wave tag (R10 path) ----
        {
            unsigned hu = (unsigned)__builtin_bit_cast(unsigned short, (f16)h);
            unsigned ot = __shfl_xor(hu, 16);
            unsigned dw = (dh & 1) ? ((ot & 0xffffu) | (hu << 16))
                                   : ((hu & 0xffffu) | (ot << 16));
            unsigned dw2 = __shfl_xor(dw, 32);
            if (do_st && t < T_ - 1) {
                u64 val = (u64)dw | ((u64)dw2 << 32);
                __hip_atomic_store((u64*)(pay + (size_t)nxt * PAYB + st_off), val,
                                   __ATOMIC_RELAXED, __HIP_MEMORY_SCOPE_AGENT);
            }
        }
        asm volatile("s_waitcnt vmcnt(0)" ::: "memory");   // payload acked at LLC
        if (l == 0 && t < T_ - 1)
            __hip_atomic_store(tag_st, (unsigned)(t + 2),
                               __ATOMIC_RELAXED, __HIP_MEMORY_SCOPE_AGENT);

        // out store off the critical path (non-temporal stream)
        __builtin_nontemporal_store(h, &out[((size_t)bglob * T_ + t) * N_ + nh]);

        cur = nxt;
        nxt = (nxt == 2) ? 0 : nxt + 1;
    }
}

// ---------------------------------------------------------------------------
extern "C" void kernel_launch(void* const* d_in, const int* in_sizes, int n_in,
                              void* d_out, int out_size, void* d_ws, size_t ws_size,
                              hipStream_t stream) {
    const float* x    = (const float*)d_in[0];
    const float* W    = (const float*)d_in[1];
    const float* bias = (const float*)d_in[2];
    float* out = (float*)d_out;

    char* ws = (char*)d_ws;
    f16*  WxT = (f16*)ws;                         // [0,4MB), dead after k_xproj
    f16*  xp  = (f16*)(ws + ((size_t)4 << 20));   // 256 MB

    const size_t need = ((size_t)4 << 20) + ((size_t)1 << 28);
    if (ws_size < need) {
        hipMemsetAsync(d_out, 0, (size_t)out_size * sizeof(float), stream);
        return;
    }

    hipLaunchKernelGGL(k_transpose_wx, dim3(512), dim3(256), 0, stream, W, WxT);
    hipLaunchKernelGGL(k_xproj, dim3(512), dim3(256), 0, stream, x, WxT, bias, xp);

    // zero the tag array (region overlaps dead WxT -> must run after k_xproj);
    // re-executes on every graph replay -> deterministic protocol start.
    hipMemsetAsync(ws + OFF_TAG, 0, 4096, stream);

    const f16* xp_c = xp;
    void* args[] = { (void*)&W, (void*)&xp_c, (void*)&ws, (void*)&out };
    hipError_t e = hipLaunchCooperativeKernel((void*)k_recur11, dim3(256), dim3(256),
                                              args, 0, stream);
    if (e != hipSuccess) {
        // high-VGPR cooperative rejection -> normal launch; grid 256 == CU
        // count, 1 WG/CU (VGPR-limited): co-residency holds without coop.
        hipLaunchKernelGGL(k_recur11, dim3(256), dim3(256), 0, stream,
                           W, xp_c, ws, out);
    }
}

// Round 12
// 2654.199 us; speedup vs baseline: 1.5767x; 1.5767x over previous
//
#include <hip/hip_runtime.h>

#define B_ 64
#define T_ 512
#define D_ 512
#define N_ 1024
#define G_ 4096   // 4*N

typedef _Float16 f16;
typedef __attribute__((ext_vector_type(8))) _Float16 f16x8;
typedef __attribute__((ext_vector_type(4))) _Float16 f16x4;
typedef __attribute__((ext_vector_type(4))) float f32x4_t;
typedef unsigned long long u64;

static __device__ __forceinline__ f32x4_t mfma16(f16x8 a, f16x8 b, f32x4_t c) {
    return __builtin_amdgcn_mfma_f32_16x16x32_f16(a, b, c, 0, 0, 0);
}

static __device__ __forceinline__ float fsig(float x) {
    return 1.f / (1.f + __expf(-x));
}
static __device__ __forceinline__ float ftanh(float x) {
    return 1.f - 2.f / (__expf(2.f * x) + 1.f);
}

// workspace map (inside first 4MB, overlapping dead WxT)
#define PAYB   131072        // one payload copy: [bg4][32KB]
#define OFF_TAG 0x60000      // 3*PAYB; tags: 4*256 u32 = 4KB

// ---------------------------------------------------------------------------
// Phase 0: WxT[g][d] = (f16) W[d][g]   (validated R1)
// ---------------------------------------------------------------------------
__global__ __launch_bounds__(256) void k_transpose_wx(const float* __restrict__ W,
                                                      f16* __restrict__ WxT) {
    __shared__ float tile[64][65];
    int bx = blockIdx.x;
    int dt = bx >> 6, gt = bx & 63;
    int d0 = dt * 64, g0 = gt * 64;
    int tid = threadIdx.x;
    for (int e = tid; e < 4096; e += 256) {
        int r = e >> 6, c = e & 63;
        tile[r][c] = W[(size_t)(d0 + r) * G_ + (g0 + c)];
    }
    __syncthreads();
    for (int e = tid; e < 4096; e += 256) {
        int r = e >> 6, c = e & 63;
        WxT[(size_t)(g0 + r) * D_ + (d0 + c)] = (f16)tile[c][r];
    }
}

// ---------------------------------------------------------------------------
// Phase 1: xp[t][g][b] = (f16)( x@Wx + bias )   (validated R1)
// ---------------------------------------------------------------------------
__global__ __launch_bounds__(256, 2) void k_xproj(const float* __restrict__ x,
                                                  const f16* __restrict__ WxT,
                                                  const float* __restrict__ bias,
                                                  f16* __restrict__ xp) {
    __shared__ __align__(16) f16 alds[64 * 512];   // 64 KB
    int t = blockIdx.x;
    int tid = threadIdx.x;
    int w = tid >> 6, l = tid & 63;

    for (int ch = tid; ch < 4096; ch += 256) {
        int b  = ch >> 6;
        int d0 = (ch & 63) << 3;
        const float* px = x + ((size_t)b * T_ + t) * D_ + d0;
        float4 v0 = *(const float4*)px;
        float4 v1 = *(const float4*)(px + 4);
        f16x8 s;
        s[0] = (f16)v0.x; s[1] = (f16)v0.y; s[2] = (f16)v0.z; s[3] = (f16)v0.w;
        s[4] = (f16)v1.x; s[5] = (f16)v1.y; s[6] = (f16)v1.z; s[7] = (f16)v1.w;
        unsigned byteoff = ((unsigned)(b * 512 + d0) * 2u) ^ ((unsigned)(b & 7) << 4);
        *(f16x8*)((char*)alds + byteoff) = s;
    }
    __syncthreads();

    const int gw = w * 1024;
    const int qk = (l >> 4) << 3;
    const int cc = l & 15;

    for (int gtb = 0; gtb < 16; ++gtb) {
        f32x4_t acc[4][4];
        #pragma unroll
        for (int a = 0; a < 4; ++a)
            #pragma unroll
            for (int m = 0; m < 4; ++m) acc[a][m] = f32x4_t{0.f, 0.f, 0.f, 0.f};

        for (int ks = 0; ks < 16; ++ks) {
            f16x8 afr[4];
            #pragma unroll
            for (int mb = 0; mb < 4; ++mb) {
                int b = mb * 16 + cc;
                int d = ks * 32 + qk;
                unsigned byteoff = ((unsigned)(b * 512 + d) * 2u) ^ ((unsigned)(b & 7) << 4);
                afr[mb] = *(const f16x8*)((const char*)alds + byteoff);
            }
            #pragma unroll
            for (int gl = 0; gl < 4; ++gl) {
                int g = gw + (gtb * 4 + gl) * 16 + cc;
                f16x8 bfr = *(const f16x8*)(WxT + (size_t)g * D_ + ks * 32 + qk);
                #pragma unroll
                for (int mb = 0; mb < 4; ++mb)
                    acc[gl][mb] = mfma16(afr[mb], bfr, acc[gl][mb]);
            }
        }
        #pragma unroll
        for (int gl = 0; gl < 4; ++gl) {
            int g = gw + (gtb * 4 + gl) * 16 + cc;
            float bg = bias[g];
            #pragma unroll
            for (int mb = 0; mb < 4; ++mb) {
                int b0 = mb * 16 + ((l >> 4) << 2);
                f16x4 sv;
                sv[0] = (f16)(acc[gl][mb][0] + bg);
                sv[1] = (f16)(acc[gl][mb][1] + bg);
                sv[2] = (f16)(acc[gl][mb][2] + bg);
                sv[3] = (f16)(acc[gl][mb][3] + bg);
                *(f16x4*)(xp + ((size_t)t * G_ + g) * B_ + b0) = sv;
            }
        }
    }
}

// ---------------------------------------------------------------------------
// Phase 2: R10 structure (validated 1.61ms) with two drain-path cuts:
//  (a) pacc double-buffered on t&1 -> trailing __syncthreads removed
//      (barrier #1 of step t+1 separates pacc[t&1] reuse at t+2).
//  (b) out stores batched 8 steps via LDS (ds_write = lgkmcnt, leaves the
//      vmcnt drain path); nt flush every 8th step -> HBM store-ack hits the
//      per-step vmcnt(0) drain on 1/8 steps only.
// Protocol (payload -> vmcnt ack -> wave tag; k-split partial wait) is
// BIT-IDENTICAL to R10. R11 lesson: keep the k-split stagger.
// ---------------------------------------------------------------------------
__global__ __launch_bounds__(256, 1) void k_recur12(const float* __restrict__ W,
                                                    const f16* __restrict__ xp,
                                                    char* __restrict__ wsb,
                                                    float* __restrict__ out) {
    __shared__ float pacc[2][4][4][16][17];   // [dbuf][kwave][ntile][batch][c15+pad]
    __shared__ float outb[4][8][64];          // 8-step out batch, 8 KB

    const int wg  = blockIdx.x;
    const int tid = threadIdx.x;
    const int w   = tid >> 6;
    const int l   = tid & 63;
    const int bg  = wg >> 6;
    const int ci  = wg & 63;

    const int lb    = l & 15;
    const int dh    = l >> 4;
    const int nh    = ci * 16 + w * 4 + dh;
    const int bglob = bg * 16 + lb;

    char*     const pay  = wsb;                      // 3 x 128 KB
    unsigned* const tags = (unsigned*)(wsb + OFF_TAG);

    // ---- Wh B-fragments into registers (mapping validated R3/R9/R10) ----
    f16x8 bf[4][8];
    {
        const int kq = l >> 4, ty = (l >> 2) & 3, dcl = l & 3;
        #pragma unroll
        for (int nt = 0; nt < 4; ++nt) {
            const int gc = ty * 1024 + ci * 16 + nt * 4 + dcl;
            #pragma unroll
            for (int kk = 0; kk < 8; ++kk) {
                #pragma unroll
                for (int i = 0; i < 8; ++i) {
                    int k = (w * 8 + kk) * 32 + kq * 8 + i;
                    bf[nt][kk][i] = (f16)W[(size_t)(D_ + k) * G_ + gc];
                }
            }
        }
    }

    // ---- producer addressing (R8/R10-validated pure-h slot layout) ----
    const int nq  = ci * 16 + w * 4;
    const int ksq = nq >> 5;
    const int q8  = (nq & 31) >> 3;
    const size_t st_off = (size_t)bg * 32768
                        + ((size_t)(ksq * 64 + q8 * 16 + lb) << 4)
                        + (size_t)(w & 1) * 8;
    const bool do_st = (dh == 0);

    // ---- consumer addressing: wave w reads k in [256w, 256w+256) ----
    const size_t ld_off = (size_t)bg * 32768 + ((size_t)(w * 8 * 64 + l) << 4);

    // tags: producer (ci, w) publishes; consumer lane l watches 64w+l
    unsigned* const tag_st = tags + (bg * 256 + ci * 4 + w);
    unsigned* const tag_ld = tags + (bg * 256 + w * 64 + l);

    // ---- init: zero payload buf0 (h_0 = 0), release, tag = 1 ----
    if (do_st)
        __hip_atomic_store((u64*)(pay + st_off), 0ull,
                           __ATOMIC_RELAXED, __HIP_MEMORY_SCOPE_AGENT);
    asm volatile("s_waitcnt vmcnt(0)" ::: "memory");
    if (l == 0)
        __hip_atomic_store(tag_st, 1u, __ATOMIC_RELAXED, __HIP_MEMORY_SCOPE_AGENT);

    __syncthreads();

    float cst = 0.f;
    int cur = 0, nxt = 1;

    for (int t = 0; t < T_; ++t) {
        const int pb = t & 1;

        // xp loads: non-temporal, issued early (HBM latency hides under poll)
        const unsigned short* xpp = (const unsigned short*)xp
                                  + (size_t)t * G_ * B_ + bglob;
        f16 xg0 = __builtin_bit_cast(f16, __builtin_nontemporal_load(xpp + (size_t)(0 * 1024 + nh) * B_));
        f16 xg1 = __builtin_bit_cast(f16, __builtin_nontemporal_load(xpp + (size_t)(1 * 1024 + nh) * B_));
        f16 xg2 = __builtin_bit_cast(f16, __builtin_nontemporal_load(xpp + (size_t)(2 * 1024 + nh) * B_));
        f16 xg3 = __builtin_bit_cast(f16, __builtin_nontemporal_load(xpp + (size_t)(3 * 1024 + nh) * B_));

        // ---- poll own 64 producer-wave tags (k-split partial wait) ----
        {
            const unsigned tgt = (unsigned)(t + 1);
            while (true) {
                unsigned v = __hip_atomic_load(tag_ld, __ATOMIC_RELAXED,
                                               __HIP_MEMORY_SCOPE_AGENT);
                if (__all(v >= tgt)) break;
                __builtin_amdgcn_s_sleep(1);
            }
        }

        // ---- payload: 8 x 16B coherent loads, once ----
        f16x8 af[8];
        {
            const char* pl = pay + (size_t)cur * PAYB + ld_off;
            #pragma unroll
            for (int kk = 0; kk < 8; ++kk)
                asm volatile("global_load_dwordx4 %0, %1, off sc0 sc1"
                             : "=&v"(af[kk]) : "v"(pl + kk * 1024) : "memory");
        }
        asm volatile("s_waitcnt vmcnt(0)" ::: "memory");
        __builtin_amdgcn_sched_barrier(0);   // rule 18: keep MFMA after the wait

        f32x4_t acc[4];
        #pragma unroll
        for (int nt = 0; nt < 4; ++nt) acc[nt] = f32x4_t{0.f, 0.f, 0.f, 0.f};
        #pragma unroll
        for (int kk = 0; kk < 8; ++kk) {
            #pragma unroll
            for (int nt = 0; nt < 4; ++nt)
                acc[nt] = mfma16(af[kk], bf[nt][kk], acc[nt]);
        }

        // ---- cross-wave K-reduction via LDS (double-buffered) ----
        {
            const int r0 = dh << 2;
            #pragma unroll
            for (int nt = 0; nt < 4; ++nt)
                #pragma unroll
                for (int j = 0; j < 4; ++j)
                    pacc[pb][w][nt][r0 + j][l & 15] = acc[nt][j];
        }
        __syncthreads();   // the ONE barrier per step

        float g0 = pacc[pb][0][w][lb][0 * 4 + dh] + pacc[pb][1][w][lb][0 * 4 + dh]
                 + pacc[pb][2][w][lb][0 * 4 + dh] + pacc[pb][3][w][lb][0 * 4 + dh] + (float)xg0;
        float g1 = pacc[pb][0][w][lb][1 * 4 + dh] + pacc[pb][1][w][lb][1 * 4 + dh]
                 + pacc[pb][2][w][lb][1 * 4 + dh] + pacc[pb][3][w][lb][1 * 4 + dh] + (float)xg1;
        float g2 = pacc[pb][0][w][lb][2 * 4 + dh] + pacc[pb][1][w][lb][2 * 4 + dh]
                 + pacc[pb][2][w][lb][2 * 4 + dh] + pacc[pb][3][w][lb][2 * 4 + dh] + (float)xg2;
        float g3 = pacc[pb][0][w][lb][3 * 4 + dh] + pacc[pb][1][w][lb][3 * 4 + dh]
                 + pacc[pb][2][w][lb][3 * 4 + dh] + pacc[pb][3][w][lb][3 * 4 + dh] + (float)xg3;

        float si = fsig(g0);
        float tj = ftanh(g1);
        float sf = fsig(g2 + 1.f);
        float so = fsig(g3);
        cst = cst * sf + si * tj;
        float h = ftanh(cst) * so;

        // ---- publish: payload stores -> wave ack -> wave tag (R10 path) ----
        {
            unsigned hu = (unsigned)__builtin_bit_cast(unsigned short, (f16)h);
            unsigned ot = __shfl_xor(hu, 16);
            unsigned dw = (dh & 1) ? ((ot & 0xffffu) | (hu << 16))
                                   : ((hu & 0xffffu) | (ot << 16));
            unsigned dw2 = __shfl_xor(dw, 32);
            if (do_st && t < T_ - 1) {
                u64 val = (u64)dw | ((u64)dw2 << 32);
                __hip_atomic_store((u64*)(pay + (size_t)nxt * PAYB + st_off), val,
                                   __ATOMIC_RELAXED, __HIP_MEMORY_SCOPE_AGENT);
            }
        }
        asm volatile("s_waitcnt vmcnt(0)" ::: "memory");   // payload acked at LLC
        if (l == 0 && t < T_ - 1)
            __hip_atomic_store(tag_st, (unsigned)(t + 2),
                               __ATOMIC_RELAXED, __HIP_MEMORY_SCOPE_AGENT);

        // ---- out: stash in LDS (lgkmcnt path), flush every 8 steps ----
        outb[w][t & 7][l] = h;
        if ((t & 7) == 7) {
            #pragma unroll
            for (int j = 0; j < 8; ++j) {
                float hv = outb[w][j][l];
                __builtin_nontemporal_store(hv,
                    &out[((size_t)bglob * T_ + (t - 7 + j)) * N_ + nh]);
            }
        }

        cur = nxt;
        nxt = (nxt == 2) ? 0 : nxt + 1;
    }
}

// ---------------------------------------------------------------------------
extern "C" void kernel_launch(void* const* d_in, const int* in_sizes, int n_in,
                              void* d_out, int out_size, void* d_ws, size_t ws_size,
                              hipStream_t stream) {
    const float* x    = (const float*)d_in[0];
    const float* W    = (const float*)d_in[1];
    const float* bias = (const float*)d_in[2];
    float* out = (float*)d_out;

    char* ws = (char*)d_ws;
    f16*  WxT = (f16*)ws;                         // [0,4MB), dead after k_xproj
    f16*  xp  = (f16*)(ws + ((size_t)4 << 20));   // 256 MB

    const size_t need = ((size_t)4 << 20) + ((size_t)1 << 28);
    if (ws_size < need) {
        hipMemsetAsync(d_out, 0, (size_t)out_size * sizeof(float), stream);
        return;
    }

    hipLaunchKernelGGL(k_transpose_wx, dim3(512), dim3(256), 0, stream, W, WxT);
    hipLaunchKernelGGL(k_xproj, dim3(512), dim3(256), 0, stream, x, WxT, bias, xp);

    // zero the tag array (region overlaps dead WxT -> must run after k_xproj);
    // re-executes on every graph replay -> deterministic protocol start.
    hipMemsetAsync(ws + OFF_TAG, 0, 4096, stream);

    const f16* xp_c = xp;
    void* args[] = { (void*)&W, (void*)&xp_c, (void*)&ws, (void*)&out };
    hipError_t e = hipLaunchCooperativeKernel((void*)k_recur12, dim3(256), dim3(256),
                                              args, 0, stream);
    if (e != hipSuccess) {
        // high-VGPR cooperative rejection -> normal launch; grid 256 == CU
        // count, 1 WG/CU: co-residency holds without coop.
        hipLaunchKernelGGL(k_recur12, dim3(256), dim3(256), 0, stream,
                           W, xp_c, ws, out);
    }
}

// Round 13
// 2018.445 us; speedup vs baseline: 2.0733x; 1.3150x over previous
//
#include <hip/hip_runtime.h>

#define B_ 64
#define T_ 512
#define D_ 512
#define N_ 1024
#define G_ 4096   // 4*N

typedef _Float16 f16;
typedef __attribute__((ext_vector_type(8))) _Float16 f16x8;
typedef __attribute__((ext_vector_type(4))) _Float16 f16x4;
typedef __attribute__((ext_vector_type(4))) float f32x4_t;
typedef unsigned long long u64;

static __device__ __forceinline__ f32x4_t mfma16(f16x8 a, f16x8 b, f32x4_t c) {
    return __builtin_amdgcn_mfma_f32_16x16x32_f16(a, b, c, 0, 0, 0);
}

static __device__ __forceinline__ float fsig(float x) {
    return 1.f / (1.f + __expf(-x));
}
static __device__ __forceinline__ float ftanh(float x) {
    return 1.f - 2.f / (__expf(2.f * x) + 1.f);
}

// LDS-visibility-only barrier: pacc exchange needs lgkm drain + s_barrier,
// NOT the full vmcnt(0) drain __syncthreads implies. Out/tag stores stay
// outstanding across it and their acks overlap the next poll.
static __device__ __forceinline__ void lds_barrier() {
    asm volatile("s_waitcnt lgkmcnt(0)" ::: "memory");
    __builtin_amdgcn_s_barrier();
    __builtin_amdgcn_sched_barrier(0);
}

// workspace map (inside first 4MB, overlapping dead WxT)
#define PAYB   131072        // one payload copy: [bg4][32KB]
#define OFF_TAG 0x60000      // 3*PAYB; tags: 4*256 u32 = 4KB

// ---------------------------------------------------------------------------
// Phase 0: WxT[g][d] = (f16) W[d][g]   (validated R1)
// ---------------------------------------------------------------------------
__global__ __launch_bounds__(256) void k_transpose_wx(const float* __restrict__ W,
                                                      f16* __restrict__ WxT) {
    __shared__ float tile[64][65];
    int bx = blockIdx.x;
    int dt = bx >> 6, gt = bx & 63;
    int d0 = dt * 64, g0 = gt * 64;
    int tid = threadIdx.x;
    for (int e = tid; e < 4096; e += 256) {
        int r = e >> 6, c = e & 63;
        tile[r][c] = W[(size_t)(d0 + r) * G_ + (g0 + c)];
    }
    __syncthreads();
    for (int e = tid; e < 4096; e += 256) {
        int r = e >> 6, c = e & 63;
        WxT[(size_t)(g0 + r) * D_ + (d0 + c)] = (f16)tile[c][r];
    }
}

// ---------------------------------------------------------------------------
// Phase 1: xp[t][g][b] = (f16)( x@Wx + bias )   (validated R1)
// ---------------------------------------------------------------------------
__global__ __launch_bounds__(256, 2) void k_xproj(const float* __restrict__ x,
                                                  const f16* __restrict__ WxT,
                                                  const float* __restrict__ bias,
                                                  f16* __restrict__ xp) {
    __shared__ __align__(16) f16 alds[64 * 512];   // 64 KB
    int t = blockIdx.x;
    int tid = threadIdx.x;
    int w = tid >> 6, l = tid & 63;

    for (int ch = tid; ch < 4096; ch += 256) {
        int b  = ch >> 6;
        int d0 = (ch & 63) << 3;
        const float* px = x + ((size_t)b * T_ + t) * D_ + d0;
        float4 v0 = *(const float4*)px;
        float4 v1 = *(const float4*)(px + 4);
        f16x8 s;
        s[0] = (f16)v0.x; s[1] = (f16)v0.y; s[2] = (f16)v0.z; s[3] = (f16)v0.w;
        s[4] = (f16)v1.x; s[5] = (f16)v1.y; s[6] = (f16)v1.z; s[7] = (f16)v1.w;
        unsigned byteoff = ((unsigned)(b * 512 + d0) * 2u) ^ ((unsigned)(b & 7) << 4);
        *(f16x8*)((char*)alds + byteoff) = s;
    }
    __syncthreads();

    const int gw = w * 1024;
    const int qk = (l >> 4) << 3;
    const int cc = l & 15;

    for (int gtb = 0; gtb < 16; ++gtb) {
        f32x4_t acc[4][4];
        #pragma unroll
        for (int a = 0; a < 4; ++a)
            #pragma unroll
            for (int m = 0; m < 4; ++m) acc[a][m] = f32x4_t{0.f, 0.f, 0.f, 0.f};

        for (int ks = 0; ks < 16; ++ks) {
            f16x8 afr[4];
            #pragma unroll
            for (int mb = 0; mb < 4; ++mb) {
                int b = mb * 16 + cc;
                int d = ks * 32 + qk;
                unsigned byteoff = ((unsigned)(b * 512 + d) * 2u) ^ ((unsigned)(b & 7) << 4);
                afr[mb] = *(const f16x8*)((const char*)alds + byteoff);
            }
            #pragma unroll
            for (int gl = 0; gl < 4; ++gl) {
                int g = gw + (gtb * 4 + gl) * 16 + cc;
                f16x8 bfr = *(const f16x8*)(WxT + (size_t)g * D_ + ks * 32 + qk);
                #pragma unroll
                for (int mb = 0; mb < 4; ++mb)
                    acc[gl][mb] = mfma16(afr[mb], bfr, acc[gl][mb]);
            }
        }
        #pragma unroll
        for (int gl = 0; gl < 4; ++gl) {
            int g = gw + (gtb * 4 + gl) * 16 + cc;
            float bg = bias[g];
            #pragma unroll
            for (int mb = 0; mb < 4; ++mb) {
                int b0 = mb * 16 + ((l >> 4) << 2);
                f16x4 sv;
                sv[0] = (f16)(acc[gl][mb][0] + bg);
                sv[1] = (f16)(acc[gl][mb][1] + bg);
                sv[2] = (f16)(acc[gl][mb][2] + bg);
                sv[3] = (f16)(acc[gl][mb][3] + bg);
                *(f16x4*)(xp + ((size_t)t * G_ + g) * B_ + b0) = sv;
            }
        }
    }
}

// ---------------------------------------------------------------------------
// Phase 2: R10 VERBATIM structure (validated 1.61ms) with ONE change:
// the two in-loop __syncthreads become lds_barrier() (lgkmcnt-only drain),
// and the out nt-store is deferred one step so its HBM ack overlaps the next
// poll instead of being drained serially at the trailing barrier.
// Protocol (payload -> vmcnt ack -> wave tag; k-split partial wait): R10.
// ---------------------------------------------------------------------------
__global__ __launch_bounds__(256, 1) void k_recur13(const float* __restrict__ W,
                                                    const f16* __restrict__ xp,
                                                    char* __restrict__ wsb,
                                                    float* __restrict__ out) {
    __shared__ float pacc[4][4][16][17];        // [kwave][ntile][batch][c15+pad]

    const int wg  = blockIdx.x;
    const int tid = threadIdx.x;
    const int w   = tid >> 6;
    const int l   = tid & 63;
    const int bg  = wg >> 6;
    const int ci  = wg & 63;

    const int lb    = l & 15;
    const int dh    = l >> 4;
    const int nh    = ci * 16 + w * 4 + dh;
    const int bglob = bg * 16 + lb;

    char*     const pay  = wsb;                      // 3 x 128 KB
    unsigned* const tags = (unsigned*)(wsb + OFF_TAG);

    // ---- Wh B-fragments into registers (mapping validated R3/R9/R10) ----
    f16x8 bf[4][8];
    {
        const int kq = l >> 4, ty = (l >> 2) & 3, dcl = l & 3;
        #pragma unroll
        for (int nt = 0; nt < 4; ++nt) {
            const int gc = ty * 1024 + ci * 16 + nt * 4 + dcl;
            #pragma unroll
            for (int kk = 0; kk < 8; ++kk) {
                #pragma unroll
                for (int i = 0; i < 8; ++i) {
                    int k = (w * 8 + kk) * 32 + kq * 8 + i;
                    bf[nt][kk][i] = (f16)W[(size_t)(D_ + k) * G_ + gc];
                }
            }
        }
    }

    // ---- producer addressing (R8/R10-validated pure-h slot layout) ----
    const int nq  = ci * 16 + w * 4;
    const int ksq = nq >> 5;
    const int q8  = (nq & 31) >> 3;
    const size_t st_off = (size_t)bg * 32768
                        + ((size_t)(ksq * 64 + q8 * 16 + lb) << 4)
                        + (size_t)(w & 1) * 8;
    const bool do_st = (dh == 0);

    // ---- consumer addressing: wave w reads k in [256w, 256w+256) ----
    const size_t ld_off = (size_t)bg * 32768 + ((size_t)(w * 8 * 64 + l) << 4);

    // tags: producer (ci, w) publishes; consumer lane l watches 64w+l
    unsigned* const tag_st = tags + (bg * 256 + ci * 4 + w);
    unsigned* const tag_ld = tags + (bg * 256 + w * 64 + l);

    // ---- init: zero payload buf0 (h_0 = 0), release, tag = 1 ----
    if (do_st)
        __hip_atomic_store((u64*)(pay + st_off), 0ull,
                           __ATOMIC_RELAXED, __HIP_MEMORY_SCOPE_AGENT);
    asm volatile("s_waitcnt vmcnt(0)" ::: "memory");
    if (l == 0)
        __hip_atomic_store(tag_st, 1u, __ATOMIC_RELAXED, __HIP_MEMORY_SCOPE_AGENT);

    __syncthreads();

    float cst = 0.f;
    int cur = 0, nxt = 1;
    float  h_prev = 0.f;
    size_t oprev  = 0;

    for (int t = 0; t < T_; ++t) {
        // deferred out store: ack overlaps this step's poll observe wait
        if (t > 0)
            __builtin_nontemporal_store(h_prev, &out[oprev]);

        // xp loads: non-temporal, issued early (HBM latency hides under poll)
        const unsigned short* xpp = (const unsigned short*)xp
                                  + (size_t)t * G_ * B_ + bglob;
        f16 xg0 = __builtin_bit_cast(f16, __builtin_nontemporal_load(xpp + (size_t)(0 * 1024 + nh) * B_));
        f16 xg1 = __builtin_bit_cast(f16, __builtin_nontemporal_load(xpp + (size_t)(1 * 1024 + nh) * B_));
        f16 xg2 = __builtin_bit_cast(f16, __builtin_nontemporal_load(xpp + (size_t)(2 * 1024 + nh) * B_));
        f16 xg3 = __builtin_bit_cast(f16, __builtin_nontemporal_load(xpp + (size_t)(3 * 1024 + nh) * B_));

        // ---- poll own 64 producer-wave tags (k-split partial wait) ----
        {
            const unsigned tgt = (unsigned)(t + 1);
            while (true) {
                unsigned v = __hip_atomic_load(tag_ld, __ATOMIC_RELAXED,
                                               __HIP_MEMORY_SCOPE_AGENT);
                if (__all(v >= tgt)) break;
                __builtin_amdgcn_s_sleep(1);
            }
        }

        // ---- payload: 8 x 16B coherent loads, once ----
        f16x8 af[8];
        {
            const char* pl = pay + (size_t)cur * PAYB + ld_off;
            #pragma unroll
            for (int kk = 0; kk < 8; ++kk)
                asm volatile("global_load_dwordx4 %0, %1, off sc0 sc1"
                             : "=&v"(af[kk]) : "v"(pl + kk * 1024) : "memory");
        }
        asm volatile("s_waitcnt vmcnt(0)" ::: "memory");
        __builtin_amdgcn_sched_barrier(0);   // rule 18: keep MFMA after the wait

        f32x4_t acc[4];
        #pragma unroll
        for (int nt = 0; nt < 4; ++nt) acc[nt] = f32x4_t{0.f, 0.f, 0.f, 0.f};
        #pragma unroll
        for (int kk = 0; kk < 8; ++kk) {
            #pragma unroll
            for (int nt = 0; nt < 4; ++nt)
                acc[nt] = mfma16(af[kk], bf[nt][kk], acc[nt]);
        }

        // ---- cross-wave K-reduction via LDS ----
        {
            const int r0 = dh << 2;
            #pragma unroll
            for (int nt = 0; nt < 4; ++nt)
                #pragma unroll
                for (int j = 0; j < 4; ++j)
                    pacc[w][nt][r0 + j][l & 15] = acc[nt][j];
        }
        lds_barrier();   // LDS-only drain: vm stores keep flying

        float g0 = pacc[0][w][lb][0 * 4 + dh] + pacc[1][w][lb][0 * 4 + dh]
                 + pacc[2][w][lb][0 * 4 + dh] + pacc[3][w][lb][0 * 4 + dh] + (float)xg0;
        float g1 = pacc[0][w][lb][1 * 4 + dh] + pacc[1][w][lb][1 * 4 + dh]
                 + pacc[2][w][lb][1 * 4 + dh] + pacc[3][w][lb][1 * 4 + dh] + (float)xg1;
        float g2 = pacc[0][w][lb][2 * 4 + dh] + pacc[1][w][lb][2 * 4 + dh]
                 + pacc[2][w][lb][2 * 4 + dh] + pacc[3][w][lb][2 * 4 + dh] + (float)xg2;
        float g3 = pacc[0][w][lb][3 * 4 + dh] + pacc[1][w][lb][3 * 4 + dh]
                 + pacc[2][w][lb][3 * 4 + dh] + pacc[3][w][lb][3 * 4 + dh] + (float)xg3;

        float si = fsig(g0);
        float tj = ftanh(g1);
        float sf = fsig(g2 + 1.f);
        float so = fsig(g3);
        cst = cst * sf + si * tj;
        float h = ftanh(cst) * so;

        // ---- publish: payload stores -> wave ack -> wave tag (R10 path) ----
        {
            unsigned hu = (unsigned)__builtin_bit_cast(unsigned short, (f16)h);
            unsigned ot = __shfl_xor(hu, 16);
            unsigned dw = (dh & 1) ? ((ot & 0xffffu) | (hu << 16))
                                   : ((hu & 0xffffu) | (ot << 16));
            unsigned dw2 = __shfl_xor(dw, 32);
            if (do_st && t < T_ - 1) {
                u64 val = (u64)dw | ((u64)dw2 << 32);
                __hip_atomic_store((u64*)(pay + (size_t)nxt * PAYB + st_off), val,
                                   __ATOMIC_RELAXED, __HIP_MEMORY_SCOPE_AGENT);
            }
        }
        asm volatile("s_waitcnt vmcnt(0)" ::: "memory");   // payload acked at LLC
        if (l == 0 && t < T_ - 1)
            __hip_atomic_store(tag_st, (unsigned)(t + 2),
                               __ATOMIC_RELAXED, __HIP_MEMORY_SCOPE_AGENT);

        // stage out store for next iteration (overlaps next poll)
        h_prev = h;
        oprev  = ((size_t)bglob * T_ + t) * N_ + nh;

        lds_barrier();   // pacc anti-dependency; tag/out acks NOT drained
        cur = nxt;
        nxt = (nxt == 2) ? 0 : nxt + 1;
    }
    __builtin_nontemporal_store(h_prev, &out[oprev]);
}

// ---------------------------------------------------------------------------
extern "C" void kernel_launch(void* const* d_in, const int* in_sizes, int n_in,
                              void* d_out, int out_size, void* d_ws, size_t ws_size,
                              hipStream_t stream) {
    const float* x    = (const float*)d_in[0];
    const float* W    = (const float*)d_in[1];
    const float* bias = (const float*)d_in[2];
    float* out = (float*)d_out;

    char* ws = (char*)d_ws;
    f16*  WxT = (f16*)ws;                         // [0,4MB), dead after k_xproj
    f16*  xp  = (f16*)(ws + ((size_t)4 << 20));   // 256 MB

    const size_t need = ((size_t)4 << 20) + ((size_t)1 << 28);
    if (ws_size < need) {
        hipMemsetAsync(d_out, 0, (size_t)out_size * sizeof(float), stream);
        return;
    }

    hipLaunchKernelGGL(k_transpose_wx, dim3(512), dim3(256), 0, stream, W, WxT);
    hipLaunchKernelGGL(k_xproj, dim3(512), dim3(256), 0, stream, x, WxT, bias, xp);

    // zero the tag array (region overlaps dead WxT -> must run after k_xproj);
    // re-executes on every graph replay -> deterministic protocol start.
    hipMemsetAsync(ws + OFF_TAG, 0, 4096, stream);

    const f16* xp_c = xp;
    void* args[] = { (void*)&W, (void*)&xp_c, (void*)&ws, (void*)&out };
    hipError_t e = hipLaunchCooperativeKernel((void*)k_recur13, dim3(256), dim3(256),
                                              args, 0, stream);
    if (e != hipSuccess) {
        // high-VGPR cooperative rejection -> normal launch; grid 256 == CU
        // count, 1 WG/CU: co-residency holds without coop.
        hipLaunchKernelGGL(k_recur13, dim3(256), dim3(256), 0, stream,
                           W, xp_c, ws, out);
    }
}